// Round 7
// baseline (777.265 us; speedup 1.0000x reference)
//
#include <hip/hip_runtime.h>
#include <math.h>

// Problem constants (setup_inputs): B=8, C=64, N=4096, O=64, K=20
#define Bn 8
#define Cc 64
#define Nn 4096
#define Oo 64
#define Kk 20
#define Kd 24                // slack list size in k_knn (exact rescore -> 20)
#define QCAP 32              // per-row candidate queue capacity per tile
#define NTOT (Bn*Nn*Kk)      // 655360 elements per BN channel

typedef __attribute__((ext_vector_type(8))) short short8;
typedef __attribute__((ext_vector_type(4))) float f32x4;
typedef __attribute__((ext_vector_type(4))) unsigned int uint4v;

__device__ __forceinline__ unsigned bf16_rn(float v) {
  unsigned u = __float_as_uint(v);
  return (u + 0x7FFFu + ((u >> 16) & 1)) >> 16;     // RN-even
}
__device__ __forceinline__ float bf2f(unsigned short u) {
  return __uint_as_float(((unsigned)u) << 16);
}
// bf16 * -2, exact for normals (sign flip + exponent+1). Zero -> -2^-126
// (harmless 1e-38-scale noise); inputs |x|<8 so no exponent overflow.
__device__ __forceinline__ short8 negdbl(short8 v) {
  uint4v u;
  __builtin_memcpy(&u, &v, 16);
  u = (u ^ 0x80008000u) + 0x00800080u;
  short8 r;
  __builtin_memcpy(&r, &u, 16);
  return r;
}

// ---------------------------------------------------------------- k_sq
__global__ __launch_bounds__(256) void k_sq(const float* __restrict__ x,
                                            float* __restrict__ sqv) {
  int g = blockIdx.x * 256 + threadIdx.x;          // g in [0, B*N)
  int b = g >> 12;
  int n = g & (Nn - 1);
  const float* xp = x + (size_t)b * Cc * Nn + n;
  float s = 0.f;
#pragma unroll
  for (int c = 0; c < Cc; c++) { float v = xp[(size_t)c * Nn]; s = fmaf(v, v, s); }
  sqv[g] = s;
}

// ---------------------------------------------------------------- k_split
// x fp32 [b][c][n] -> 3-term bf16 split, transposed to [b][n][c]:
//   h = RN(x); m = RN(x-h); l = RN(x-h-m)   (x-h, x-h-m exact in fp32)
// Gram uses h,m only; l is kept for the exact rescore reconstruction.
__global__ __launch_bounds__(256) void k_split(const float* __restrict__ x,
                                               unsigned short* __restrict__ xhi,
                                               unsigned short* __restrict__ xmid,
                                               unsigned short* __restrict__ xlo) {
  __shared__ float xs[64][65];
  int tid = threadIdx.x;
  int b = blockIdx.x & 7;
  int n0 = (blockIdx.x >> 3) << 6;
  for (int i = 0; i < 16; i++) {
    int c = i * 4 + (tid >> 6);
    int n = tid & 63;
    xs[c][n] = x[((size_t)b * Cc + c) * Nn + n0 + n];
  }
  __syncthreads();
  for (int i = 0; i < 16; i++) {
    int n = i * 4 + (tid >> 6);
    int c = tid & 63;
    float v = xs[c][n];
    unsigned hb = bf16_rn(v);
    float hf = __uint_as_float(hb << 16);
    float r1 = v - hf;                                       // exact
    unsigned mb = bf16_rn(r1);
    float mf = __uint_as_float(mb << 16);
    float r2 = r1 - mf;                                      // exact
    unsigned lb = bf16_rn(r2);
    size_t o = ((size_t)(b << 12) + n0 + n) * 64 + c;
    xhi[o] = (unsigned short)hb;
    xmid[o] = (unsigned short)mb;
    xlo[o] = (unsigned short)lb;
  }
}

// ---------------------------------------------------------------- k_y1z
__global__ __launch_bounds__(256) void k_y1z(const float* __restrict__ x,
                                             const float* __restrict__ Wm,
                                             float* __restrict__ y1,
                                             float* __restrict__ z) {
  __shared__ float xs[64][64];
  __shared__ float Wl[64][129];
  int tid = threadIdx.x;
  int b = blockIdx.x & 7;
  int n0 = (blockIdx.x >> 3) << 6;
  for (int i = tid; i < 64 * 128; i += 256) Wl[i >> 7][i & 127] = Wm[i];
  for (int i = 0; i < 16; i++) {
    int c = i * 4 + (tid >> 6);
    int n = tid & 63;
    xs[c][n] = x[((size_t)b * Cc + c) * Nn + n0 + n];
  }
  __syncthreads();
  int o = tid & 63, ng = tid >> 6;
  for (int p = 0; p < 16; p++) {
    int n = ng + p * 4;
    float a1 = 0.f, a2 = 0.f;
#pragma unroll 8
    for (int c = 0; c < 64; c++) {
      float xv = xs[c][n];
      a1 = fmaf(xv, Wl[o][c], a1);
      a2 = fmaf(xv, Wl[o][64 + c], a2);
    }
    size_t off = ((size_t)b * Nn + n0 + n) * 64 + o;
    y1[off] = a1;
    z[off] = a2 - a1;
  }
}

// ---------------------------------------------------------------- k_knn (v7)
// 2-term split-bf16 MFMA Gram producing keys DIRECTLY:
//   A-frags pre-scaled by -2 (negdbl), accumulators preloaded with sq[m]
//   -> acc = sq[m] - 2*(hh+hm+mh+mm)  (key; error ~6e-4, absorbed by k_rescore)
// Top-Kd=24 wave-private queue/handler machinery (round 6). LDS ~52KB.
__global__ __launch_bounds__(256, 2) void k_knn(const unsigned short* __restrict__ xhi,
                                                const unsigned short* __restrict__ xmid,
                                                const float* __restrict__ sqv,
                                                int* __restrict__ idx24) {
  __shared__ alignas(16) short Bs[2][128][72];   // [h/m][m][c], padded
  __shared__ float thrS[64];
  __shared__ float sqs[128];
  __shared__ alignas(16) float qk[64][36];       // 144B rows, 16B aligned
  __shared__ alignas(8) unsigned short qm[64][36];
  __shared__ int qcnt[64];

  const int tid = threadIdx.x;
  const int lane = tid & 63;
  const int w = tid >> 6;
  const int b = blockIdx.x & 7;                  // XCD swizzle: batch per XCD
  const int n0 = (blockIdx.x >> 3) << 6;
  const int lm = lane & 15;                      // candidate col / A row
  const int q = lane >> 4;                       // quad: k-subrange selector
  const int myrow = w * 16 + lm;                 // row drained by this lane
  const bool handler = (lane < 16);

  // handler state (meaningful on lanes 0-15 of each wave)
  float hk[Kd];
  int hix[Kd];
  float hthr = INFINITY;
#pragma unroll
  for (int kk = 0; kk < Kd; kk++) { hk[kk] = INFINITY; hix[kk] = 0; }

  if (handler) { thrS[myrow] = INFINITY; qcnt[myrow] = 0; }  // wave-private init

  // A fragments (pre-scaled by -2): wave w owns query rows n0+w*16 .. +15
  const size_t arow = ((size_t)(b << 12) + n0 + w * 16 + lm) * 64;
  short8 ah0 = negdbl(*(const short8*)&xhi[arow + q * 8]);
  short8 ah1 = negdbl(*(const short8*)&xhi[arow + 32 + q * 8]);
  short8 am0 = negdbl(*(const short8*)&xmid[arow + q * 8]);
  short8 am1 = negdbl(*(const short8*)&xmid[arow + 32 + q * 8]);

  f32x4 acc[8];

  for (int m0 = 0; m0 < Nn; m0 += 128) {
    __syncthreads();                              // all waves done reading Bs
    // stage B tile: 2 layers x 128 rows x 8 chunks of short8, coalesced
#pragma unroll
    for (int i = 0; i < 8; i++) {
      int f = i * 256 + tid;                      // [0,2048); layer uniform/i
      int layer = f >> 10;
      int r = (f >> 3) & 127;
      int qq = f & 7;
      const unsigned short* src = layer ? xmid : xhi;
      short8 v = *(const short8*)&src[((size_t)(b << 12) + m0 + r) * 64 + qq * 8];
      *(short8*)&Bs[layer][r][qq * 8] = v;
    }
    if (tid < 32) ((float4*)sqs)[tid] = ((const float4*)(sqv + b * Nn + m0))[tid];
    __syncthreads();                              // staging visible

#pragma unroll
    for (int g = 0; g < 8; g++) {
      const int mr = g * 16 + lm;
      float sv = sqs[mr];
      short8 bh0 = *(const short8*)&Bs[0][mr][q * 8];
      short8 bh1 = *(const short8*)&Bs[0][mr][32 + q * 8];
      short8 bm0 = *(const short8*)&Bs[1][mr][q * 8];
      short8 bm1 = *(const short8*)&Bs[1][mr][32 + q * 8];
      f32x4 a = (f32x4){sv, sv, sv, sv};          // key = sq[m] + (-2A)·B
      a = __builtin_amdgcn_mfma_f32_16x16x32_bf16(am0, bm0, a, 0, 0, 0);  // mm
      a = __builtin_amdgcn_mfma_f32_16x16x32_bf16(am1, bm1, a, 0, 0, 0);
      a = __builtin_amdgcn_mfma_f32_16x16x32_bf16(am0, bh0, a, 0, 0, 0);  // mh
      a = __builtin_amdgcn_mfma_f32_16x16x32_bf16(am1, bh1, a, 0, 0, 0);
      a = __builtin_amdgcn_mfma_f32_16x16x32_bf16(ah0, bm0, a, 0, 0, 0);  // hm
      a = __builtin_amdgcn_mfma_f32_16x16x32_bf16(ah1, bm1, a, 0, 0, 0);
      a = __builtin_amdgcn_mfma_f32_16x16x32_bf16(ah0, bh0, a, 0, 0, 0);  // hh
      a = __builtin_amdgcn_mfma_f32_16x16x32_bf16(ah1, bh1, a, 0, 0, 0);
      acc[g] = a;
    }

    // pend bitmask of below-threshold candidates (keys already in acc)
    unsigned pend = 0;
    {
      float tl[4];
#pragma unroll
      for (int r = 0; r < 4; r++) tl[r] = thrS[w * 16 + q * 4 + r];
#pragma unroll
      for (int g = 0; g < 8; g++)
#pragma unroll
        for (int r = 0; r < 4; r++)
          if (acc[g][r] < tl[r]) pend |= 1u << (g * 4 + r);
    }

    // wave-private push / drain: NO __syncthreads (DS in-order per wave)
    for (;;) {
      if (pend) {
#pragma unroll
        for (int g = 0; g < 8; g++) {
#pragma unroll
          for (int r = 0; r < 4; r++) {
            unsigned bit = 1u << (g * 4 + r);
            if (pend & bit) {
              int row = w * 16 + q * 4 + r;
              int p = atomicAdd(&qcnt[row], 1);
              if (p < QCAP) {
                qk[row][p] = acc[g][r];
                qm[row][p] = (unsigned short)(m0 + g * 16 + lm);
                pend &= ~bit;
              }
              // else: bit stays set -> retry after drain
            }
          }
        }
      }
      unsigned long long anyovf = __ballot(pend != 0);

      if (handler) {                             // 16 lanes drain 16 rows
        int cn = qcnt[myrow];
        if (cn > QCAP) cn = QCAP;
        for (int p0 = 0; p0 < cn; p0 += 4) {
          float4 kv4 = *(const float4*)&qk[myrow][p0];
          ushort4 mv4 = *(const ushort4*)&qm[myrow][p0];
          float kva[4] = {kv4.x, kv4.y, kv4.z, kv4.w};
          unsigned short mva[4] = {mv4.x, mv4.y, mv4.z, mv4.w};
#pragma unroll
          for (int j = 0; j < 4; j++) {
            if (p0 + j < cn && kva[j] < hthr) {
              float kv = kva[j];
              int mvi = (int)mva[j];
              float mx = -INFINITY, mx2 = -INFINITY;
              int sl = 0;
#pragma unroll
              for (int kk = 0; kk < Kd; kk++) {
                float v = hk[kk];
                if (v > mx) { mx2 = mx; mx = v; sl = kk; }
                else if (v > mx2) mx2 = v;
              }
#pragma unroll
              for (int kk = 0; kk < Kd; kk++) {
                bool hit = (kk == sl);
                hk[kk] = hit ? kv : hk[kk];
                hix[kk] = hit ? mvi : hix[kk];
              }
              hthr = fmaxf(mx2, kv);
            }
          }
        }
        if (cn) { qcnt[myrow] = 0; thrS[myrow] = hthr; }
      }
      if (!anyovf) break;
      // refilter surviving bits against the tightened thresholds
      {
        float tl[4];
#pragma unroll
        for (int r = 0; r < 4; r++) tl[r] = thrS[w * 16 + q * 4 + r];
#pragma unroll
        for (int g = 0; g < 8; g++)
#pragma unroll
          for (int r = 0; r < 4; r++) {
            unsigned bit = 1u << (g * 4 + r);
            if ((pend & bit) && acc[g][r] >= tl[r]) pend &= ~bit;
          }
      }
    }
  }

  // final write: 24 approx-best indices per row (order irrelevant)
  if (handler) {
    size_t base = ((size_t)b * Nn + n0 + myrow) * Kd;
#pragma unroll
    for (int kk = 0; kk < Kd; kk++) idx24[base + kk] = hix[kk];
  }
}

// ---------------------------------------------------------------- k_rescore
// Exact selection: for each row, recompute its 24 candidate keys with
// 3-term-reconstructed fp32 dots (error ~2^-24 class), drop the 4 largest,
// write the exact top-20. Wave = 2 rows (lanes 0-23 / 32-55 active).
__global__ __launch_bounds__(256) void k_rescore(const unsigned short* __restrict__ xhi,
                                                 const unsigned short* __restrict__ xmid,
                                                 const unsigned short* __restrict__ xlo,
                                                 const float* __restrict__ sqv,
                                                 const int* __restrict__ idx24,
                                                 int* __restrict__ idxout) {
  const int tid = threadIdx.x;
  const int lane = tid & 63;
  const int w = tid >> 6;
  const int grp = lane >> 5;                     // row within wave
  const int cl = lane & 31;                      // candidate lane in group
  const long long rowg = (long long)blockIdx.x * 8 + w * 2 + grp;
  const int b = (int)(rowg >> 12);
  const bool act = cl < Kd;

  // a-side: reconstruct this row's 64 dims (all lanes of group: same row)
  const size_t abase = (size_t)rowg * 64;
  float av[64];
#pragma unroll
  for (int d8 = 0; d8 < 8; d8++) {
    short8 h = *(const short8*)&xhi[abase + d8 * 8];
    short8 m = *(const short8*)&xmid[abase + d8 * 8];
    short8 l = *(const short8*)&xlo[abase + d8 * 8];
#pragma unroll
    for (int j = 0; j < 8; j++)
      av[d8 * 8 + j] = bf2f((unsigned short)h[j]) + bf2f((unsigned short)m[j]) +
                       bf2f((unsigned short)l[j]);
  }

  int mi = act ? idx24[rowg * Kd + cl] : 0;
  const size_t bbase = ((size_t)(b << 12) + mi) * 64;
  float dot = 0.f;
#pragma unroll
  for (int d8 = 0; d8 < 8; d8++) {
    short8 h = *(const short8*)&xhi[bbase + d8 * 8];
    short8 m = *(const short8*)&xmid[bbase + d8 * 8];
    short8 l = *(const short8*)&xlo[bbase + d8 * 8];
#pragma unroll
    for (int j = 0; j < 8; j++) {
      float bv = bf2f((unsigned short)h[j]) + bf2f((unsigned short)m[j]) +
                 bf2f((unsigned short)l[j]);
      dot = fmaf(av[d8 * 8 + j], bv, dot);
    }
  }
  float key = act ? fmaf(-2.f, dot, sqv[(b << 12) + mi]) : -INFINITY;

  // drop the 4 largest (inactive lanes = -INF never win the max)
  float k2 = key;
#pragma unroll
  for (int it = 0; it < Kd - Kk; it++) {
    float mx = k2;
#pragma unroll
    for (int s = 1; s < 32; s <<= 1) mx = fmaxf(mx, __shfl_xor(mx, s));
    unsigned long long msk = __ballot(k2 == mx);
    unsigned gm = (unsigned)(grp ? (msk >> 32) : msk);
    int victim = __ffs(gm) - 1;
    if (cl == victim) k2 = -INFINITY;
  }
  bool keep = act && (k2 != -INFINITY);
  unsigned long long sm = __ballot(keep);
  unsigned gsm = (unsigned)(grp ? (sm >> 32) : sm);
  if (keep) {
    int pos = __popc(gsm & ((1u << cl) - 1u));    // exactly 20 survivors
    idxout[rowg * Kk + pos] = mi;
  }
}

// ---------------------------------------------------------------- k_stats
// Per-block partial sums (no global atomic contention); k_reduce finishes.
__global__ __launch_bounds__(256) void k_stats(const float* __restrict__ y1,
                                               const float* __restrict__ z,
                                               const int* __restrict__ idxp,
                                               float* __restrict__ parts) {
  __shared__ float rs[4][64];
  __shared__ float rq[4][64];
  int tid = threadIdx.x;
  int o = tid & 63, g = tid >> 6;
  int b = blockIdx.x & 7;                       // XCD swizzle
  int n0 = (blockIdx.x >> 3) << 6;
  const float* y1b = y1 + (size_t)b * Nn * 64;
  float s = 0.f, ss = 0.f;
  for (int t = 0; t < 16; t++) {
    int n = n0 + g + t * 4;
    size_t base = (size_t)b * Nn + n;
    float zv = z[base * 64 + o];
    const int* ip = idxp + base * Kk;
#pragma unroll
    for (int k = 0; k < Kk; k++) {
      int j = ip[k];
      float hv = y1b[(size_t)j * 64 + o] + zv;
      s += hv;
      ss = fmaf(hv, hv, ss);
    }
  }
  rs[g][o] = s;
  rq[g][o] = ss;
  __syncthreads();
  if (tid < 64) {
    parts[(size_t)blockIdx.x * 128 + tid] = rs[0][tid] + rs[1][tid] + rs[2][tid] + rs[3][tid];
    parts[(size_t)blockIdx.x * 128 + 64 + tid] = rq[0][tid] + rq[1][tid] + rq[2][tid] + rq[3][tid];
  }
}

// ---------------------------------------------------------------- k_reduce
__global__ __launch_bounds__(128) void k_reduce(const float* __restrict__ parts,
                                                float* __restrict__ stats) {
  int tid = threadIdx.x;                         // [0,128)
  float s = 0.f;
  for (int i = 0; i < 512; i += 4) {
    s += parts[(size_t)i * 128 + tid] + parts[(size_t)(i + 1) * 128 + tid] +
         parts[(size_t)(i + 2) * 128 + tid] + parts[(size_t)(i + 3) * 128 + tid];
  }
  stats[tid] = s;
}

// ---------------------------------------------------------------- k_out
__global__ __launch_bounds__(256) void k_out(const float* __restrict__ y1,
                                             const float* __restrict__ z,
                                             const int* __restrict__ idxp,
                                             const float* __restrict__ stats,
                                             const float* __restrict__ gamma,
                                             const float* __restrict__ beta,
                                             float* __restrict__ out) {
  __shared__ float T[64][65];
  int tid = threadIdx.x;
  int lane = tid & 63;
  int w = tid >> 6;
  int b = blockIdx.x & 7;                       // XCD swizzle
  int n0 = (blockIdx.x >> 3) << 6;
  int o = lane;
  const float inv = 1.0f / (float)NTOT;
  float mean = stats[o] * inv;
  float var = fmaf(-mean, mean, stats[64 + o] * inv);
  float sc = gamma[o] * rsqrtf(var + 1e-5f);
  float bi = fmaf(-mean, sc, beta[o]);
  const float* y1b = y1 + (size_t)b * Nn * 64;
  for (int t = 0; t < 16; t++) {
    int nl = w + t * 4;
    size_t base = (size_t)b * Nn + n0 + nl;
    float zv = z[base * 64 + o];
    const int* ip = idxp + base * Kk;
    float mv = -INFINITY;
#pragma unroll
    for (int k = 0; k < Kk; k++) {
      int j = ip[k];
      float hv = y1b[(size_t)j * 64 + o] + zv;
      float hn = fmaf(hv, sc, bi);
      float a = (hn >= 0.f) ? hn : 0.2f * hn;
      mv = fmaxf(mv, a);
    }
    T[o][nl] = mv;
  }
  __syncthreads();
  for (int t = 0; t < 16; t++) {
    int oo = w * 16 + t;
    out[((size_t)b * Oo + oo) * Nn + n0 + lane] = T[oo][lane];
  }
}

// ---------------------------------------------------------------- launch
extern "C" void kernel_launch(void* const* d_in, const int* in_sizes, int n_in,
                              void* d_out, int out_size, void* d_ws, size_t ws_size,
                              hipStream_t stream) {
  const float* x = (const float*)d_in[0];
  const float* W = (const float*)d_in[1];
  const float* gamma = (const float*)d_in[2];
  const float* beta = (const float*)d_in[3];
  // d_in[4] is k (=20), baked in as Kk.

  // workspace layout (bytes):
  //   xhi  : [0,        4194304)  bf16 [b][n][c]  \ dead after k_rescore;
  //   xmid : [4194304,  8388608)  bf16 [b][n][c]   } y1 overlays [0,8M),
  //   xlo  : [8388608, 12582912)  bf16 [b][n][c]  / z overlays [8M,16M)
  //   idx24: [12582912,15728640)  B*N*24 int32  (inside future z region; dead
  //                                              before k_y1z writes z)
  //   y1   : [0,        8388608)  B*N*O fp32  (k_y1z, after k_rescore)
  //   z    : [8388608, 16777216)  B*N*O fp32  (k_y1z, after k_rescore)
  //   sq   : [16777216,16908288)  B*N fp32
  //   stats: [16908288,16908800)  128 fp32
  //   idx20: [16908800,19530240)  B*N*K int32
  //   parts: [19530240,19792384)  512*128 fp32
  char* ws = (char*)d_ws;
  unsigned short* xhi = (unsigned short*)ws;
  unsigned short* xmid = (unsigned short*)(ws + 4194304);
  unsigned short* xlo = (unsigned short*)(ws + 8388608);
  int* idx24 = (int*)(ws + 12582912);
  float* y1 = (float*)ws;
  float* z = (float*)(ws + 8388608);
  float* sq = (float*)(ws + 16777216);
  float* stats = (float*)(ws + 16908288);
  int* idx = (int*)(ws + 16908800);
  float* parts = (float*)(ws + 19530240);
  float* out = (float*)d_out;

  k_split<<<Bn * (Nn / 64), 256, 0, stream>>>(x, xhi, xmid, xlo);
  k_sq<<<(Bn * Nn) / 256, 256, 0, stream>>>(x, sq);
  k_knn<<<Bn * (Nn / 64), 256, 0, stream>>>(xhi, xmid, sq, idx24);
  k_rescore<<<(Bn * Nn) / 8, 256, 0, stream>>>(xhi, xmid, xlo, sq, idx24, idx);
  k_y1z<<<Bn * (Nn / 64), 256, 0, stream>>>(x, W, y1, z);
  k_stats<<<Bn * (Nn / 64), 256, 0, stream>>>(y1, z, idx, parts);
  k_reduce<<<1, 128, 0, stream>>>(parts, stats);
  k_out<<<Bn * (Nn / 64), 256, 0, stream>>>(y1, z, idx, stats, gamma, beta, out);
}

// Round 8
// 566.083 us; speedup vs baseline: 1.3731x; 1.3731x over previous
//
#include <hip/hip_runtime.h>
#include <math.h>

// Problem constants (setup_inputs): B=8, C=64, N=4096, O=64, K=20
#define Bn 8
#define Cc 64
#define Nn 4096
#define Oo 64
#define Kk 20
#define QCAP 24              // per-row candidate queue capacity per tile
#define NTOT (Bn*Nn*Kk)      // 655360 elements per BN channel

typedef __attribute__((ext_vector_type(8))) short short8;
typedef __attribute__((ext_vector_type(4))) float f32x4;

__device__ __forceinline__ unsigned bf16_rn(float v) {
  unsigned u = __float_as_uint(v);
  return (u + 0x7FFFu + ((u >> 16) & 1)) >> 16;     // RN-even
}

// ---------------------------------------------------------------- k_sq
__global__ __launch_bounds__(256) void k_sq(const float* __restrict__ x,
                                            float* __restrict__ sqv) {
  int g = blockIdx.x * 256 + threadIdx.x;          // g in [0, B*N)
  int b = g >> 12;
  int n = g & (Nn - 1);
  const float* xp = x + (size_t)b * Cc * Nn + n;
  float s = 0.f;
#pragma unroll
  for (int c = 0; c < Cc; c++) { float v = xp[(size_t)c * Nn]; s = fmaf(v, v, s); }
  sqv[g] = s;
}

// ---------------------------------------------------------------- k_split
// x fp32 [b][c][n] -> 3-term bf16 split, transposed to [b][n][c]:
//   h = RN(x); m = RN(x-h); l = RN(x-h-m)   (x-h, x-h-m exact in fp32)
__global__ __launch_bounds__(256) void k_split(const float* __restrict__ x,
                                               unsigned short* __restrict__ xhi,
                                               unsigned short* __restrict__ xmid,
                                               unsigned short* __restrict__ xlo) {
  __shared__ float xs[64][65];
  int tid = threadIdx.x;
  int b = blockIdx.x & 7;
  int n0 = (blockIdx.x >> 3) << 6;
  for (int i = 0; i < 16; i++) {
    int c = i * 4 + (tid >> 6);
    int n = tid & 63;
    xs[c][n] = x[((size_t)b * Cc + c) * Nn + n0 + n];
  }
  __syncthreads();
  for (int i = 0; i < 16; i++) {
    int n = i * 4 + (tid >> 6);
    int c = tid & 63;
    float v = xs[c][n];
    unsigned hb = bf16_rn(v);
    float hf = __uint_as_float(hb << 16);
    float r1 = v - hf;                                       // exact
    unsigned mb = bf16_rn(r1);
    float mf = __uint_as_float(mb << 16);
    float r2 = r1 - mf;                                      // exact
    unsigned lb = bf16_rn(r2);
    size_t o = ((size_t)(b << 12) + n0 + n) * 64 + c;
    xhi[o] = (unsigned short)hb;
    xmid[o] = (unsigned short)mb;
    xlo[o] = (unsigned short)lb;
  }
}

// ---------------------------------------------------------------- k_y1z
__global__ __launch_bounds__(256) void k_y1z(const float* __restrict__ x,
                                             const float* __restrict__ Wm,
                                             float* __restrict__ y1,
                                             float* __restrict__ z) {
  __shared__ float xs[64][64];
  __shared__ float Wl[64][129];
  int tid = threadIdx.x;
  int b = blockIdx.x & 7;
  int n0 = (blockIdx.x >> 3) << 6;
  for (int i = tid; i < 64 * 128; i += 256) Wl[i >> 7][i & 127] = Wm[i];
  for (int i = 0; i < 16; i++) {
    int c = i * 4 + (tid >> 6);
    int n = tid & 63;
    xs[c][n] = x[((size_t)b * Cc + c) * Nn + n0 + n];
  }
  __syncthreads();
  int o = tid & 63, ng = tid >> 6;
  for (int p = 0; p < 16; p++) {
    int n = ng + p * 4;
    float a1 = 0.f, a2 = 0.f;
#pragma unroll 8
    for (int c = 0; c < 64; c++) {
      float xv = xs[c][n];
      a1 = fmaf(xv, Wl[o][c], a1);
      a2 = fmaf(xv, Wl[o][64 + c], a2);
    }
    size_t off = ((size_t)b * Nn + n0 + n) * 64 + o;
    y1[off] = a1;
    z[off] = a2 - a1;
  }
}

// ---------------------------------------------------------------- k_knn (v8)
// 3-term split-bf16 MFMA Gram (exact-class keys, round 6 numerics) with
// 8-ROW WAVES for occupancy: 32-row/256-thread blocks, 64-col B tiles,
// grid 1024 -> 4 blocks/CU = 16 waves/CU (round 6/7 ran 8 waves/CU at
// VALUBusy ~50% = latency-starved). MFMA A-rows 8-15 duplicate rows 0-7
// (2x MFMA work, pipe-parallel with VALU); candidates from duplicate C-rows
// (q>=2) are discarded. Top-k: wave-private queues + 8 handler lanes/wave
// holding SORTED 20-lists in registers (insert = cmp+shift chain ~60 instr,
// thr = hk[19] free). LDS ~33KB.
__global__ __launch_bounds__(256, 4) void k_knn(const unsigned short* __restrict__ xhi,
                                                const unsigned short* __restrict__ xmid,
                                                const unsigned short* __restrict__ xlo,
                                                const float* __restrict__ sqv,
                                                int* __restrict__ idxout) {
  __shared__ alignas(16) short Bs[3][64][72];    // [h/m/l][m][c], padded
  __shared__ float thrS[32];
  __shared__ float sqs[64];
  __shared__ alignas(16) float qk[32][28];       // stride 28: handler lanes bank-distinct
  __shared__ alignas(8) unsigned short qm[32][28];
  __shared__ int qcnt[32];

  const int tid = threadIdx.x;
  const int lane = tid & 63;
  const int w = tid >> 6;
  const int b = blockIdx.x & 7;                  // XCD swizzle: batch per XCD
  const int n0 = (blockIdx.x >> 3) << 5;         // 128 row-blocks x 32 rows
  const int lm = lane & 15;                      // candidate col / A row slot
  const int q = lane >> 4;                       // quad: C row = q*4+r
  const int myrow = w * 8 + lane;                // valid for lane<8 (handler)
  const bool handler = (lane < 8);

  // handler state: SORTED ascending 20-list in registers (lanes 0-7)
  float hk[Kk];
  int hix[Kk];
  float hthr = INFINITY;
#pragma unroll
  for (int kk = 0; kk < Kk; kk++) { hk[kk] = INFINITY; hix[kk] = 0; }

  if (handler) { thrS[myrow] = INFINITY; qcnt[myrow] = 0; }  // wave-private init

  // A fragments: wave w owns query rows n0+w*8 .. +7; rows 8-15 duplicate.
  const size_t arow = ((size_t)(b << 12) + n0 + w * 8 + (lm & 7)) * 64;
  short8 ah0 = *(const short8*)&xhi[arow + q * 8];
  short8 ah1 = *(const short8*)&xhi[arow + 32 + q * 8];
  short8 am0 = *(const short8*)&xmid[arow + q * 8];
  short8 am1 = *(const short8*)&xmid[arow + 32 + q * 8];
  short8 al0 = *(const short8*)&xlo[arow + q * 8];
  short8 al1 = *(const short8*)&xlo[arow + 32 + q * 8];

  f32x4 acc[4];

  for (int m0 = 0; m0 < Nn; m0 += 64) {
    __syncthreads();                              // all waves done reading Bs
    // stage B tile: 3 layers x 64 rows x 8 chunks of short8, coalesced
#pragma unroll
    for (int i = 0; i < 6; i++) {
      int f = i * 256 + tid;                      // [0,1536)
      int layer = f >> 9;
      int r = (f >> 3) & 63;
      int qq = f & 7;
      const unsigned short* src = (layer == 0) ? xhi : (layer == 1) ? xmid : xlo;
      short8 v = *(const short8*)&src[((size_t)(b << 12) + m0 + r) * 64 + qq * 8];
      *(short8*)&Bs[layer][r][qq * 8] = v;
    }
    if (tid < 16) ((float4*)sqs)[tid] = ((const float4*)(sqv + b * Nn + m0))[tid];
    __syncthreads();                              // staging visible

#pragma unroll
    for (int g = 0; g < 4; g++) {
      const int mr = g * 16 + lm;
      short8 bh0 = *(const short8*)&Bs[0][mr][q * 8];
      short8 bh1 = *(const short8*)&Bs[0][mr][32 + q * 8];
      short8 bm0 = *(const short8*)&Bs[1][mr][q * 8];
      short8 bm1 = *(const short8*)&Bs[1][mr][32 + q * 8];
      short8 bl0 = *(const short8*)&Bs[2][mr][q * 8];
      short8 bl1 = *(const short8*)&Bs[2][mr][32 + q * 8];
      f32x4 a = (f32x4){0.f, 0.f, 0.f, 0.f};
      a = __builtin_amdgcn_mfma_f32_16x16x32_bf16(am0, bm0, a, 0, 0, 0);  // mm
      a = __builtin_amdgcn_mfma_f32_16x16x32_bf16(am1, bm1, a, 0, 0, 0);
      a = __builtin_amdgcn_mfma_f32_16x16x32_bf16(ah0, bl0, a, 0, 0, 0);  // hl
      a = __builtin_amdgcn_mfma_f32_16x16x32_bf16(ah1, bl1, a, 0, 0, 0);
      a = __builtin_amdgcn_mfma_f32_16x16x32_bf16(al0, bh0, a, 0, 0, 0);  // lh
      a = __builtin_amdgcn_mfma_f32_16x16x32_bf16(al1, bh1, a, 0, 0, 0);
      a = __builtin_amdgcn_mfma_f32_16x16x32_bf16(ah0, bm0, a, 0, 0, 0);  // hm
      a = __builtin_amdgcn_mfma_f32_16x16x32_bf16(ah1, bm1, a, 0, 0, 0);
      a = __builtin_amdgcn_mfma_f32_16x16x32_bf16(am0, bh0, a, 0, 0, 0);  // mh
      a = __builtin_amdgcn_mfma_f32_16x16x32_bf16(am1, bh1, a, 0, 0, 0);
      a = __builtin_amdgcn_mfma_f32_16x16x32_bf16(ah0, bh0, a, 0, 0, 0);  // hh
      a = __builtin_amdgcn_mfma_f32_16x16x32_bf16(ah1, bh1, a, 0, 0, 0);
      acc[g] = a;
    }

    // keys = sq[m] - 2*dot; only q<2 lanes hold unique query rows (0..7)
    unsigned pend = 0;
    if (q < 2) {
      float tl[4];
#pragma unroll
      for (int r = 0; r < 4; r++) tl[r] = thrS[w * 8 + q * 4 + r];
#pragma unroll
      for (int g = 0; g < 4; g++) {
        float sv = sqs[g * 16 + lm];
#pragma unroll
        for (int r = 0; r < 4; r++) {
          float key = fmaf(-2.f, acc[g][r], sv);
          acc[g][r] = key;
          if (key < tl[r]) pend |= 1u << (g * 4 + r);
        }
      }
    }

    // wave-private push / drain: NO __syncthreads (DS in-order per wave)
    for (;;) {
      if (pend) {
#pragma unroll
        for (int g = 0; g < 4; g++) {
#pragma unroll
          for (int r = 0; r < 4; r++) {
            unsigned bit = 1u << (g * 4 + r);
            if (pend & bit) {
              int row = w * 8 + q * 4 + r;
              int p = atomicAdd(&qcnt[row], 1);
              if (p < QCAP) {
                qk[row][p] = acc[g][r];
                qm[row][p] = (unsigned short)(m0 + g * 16 + lm);
                pend &= ~bit;
              }
              // else: bit stays set -> retry after drain
            }
          }
        }
      }
      unsigned long long anyovf = __ballot(pend != 0);

      if (handler) {                             // 8 lanes drain 8 rows
        int cn = qcnt[myrow];
        if (cn > QCAP) cn = QCAP;
        for (int p0 = 0; p0 < cn; p0 += 4) {
          float4 kv4 = *(const float4*)&qk[myrow][p0];
          ushort4 mv4 = *(const ushort4*)&qm[myrow][p0];
          float kva[4] = {kv4.x, kv4.y, kv4.z, kv4.w};
          unsigned short mva[4] = {mv4.x, mv4.y, mv4.z, mv4.w};
#pragma unroll
          for (int j = 0; j < 4; j++) {
            if (p0 + j < cn && kva[j] < hthr) {
              float kv = kva[j];
              int mvi = (int)mva[j];
              bool cm[Kk];
#pragma unroll
              for (int kk = 0; kk < Kk; kk++) cm[kk] = kv < hk[kk];
#pragma unroll
              for (int kk = Kk - 1; kk >= 1; kk--) {
                hk[kk]  = cm[kk] ? (cm[kk - 1] ? hk[kk - 1]  : kv ) : hk[kk];
                hix[kk] = cm[kk] ? (cm[kk - 1] ? hix[kk - 1] : mvi) : hix[kk];
              }
              if (cm[0]) { hk[0] = kv; hix[0] = mvi; }
              hthr = hk[Kk - 1];
            }
          }
        }
        if (cn) { qcnt[myrow] = 0; thrS[myrow] = hthr; }
      }
      if (!anyovf) break;
      // refilter surviving bits against the tightened thresholds
      if (pend) {
        float tl[4];
#pragma unroll
        for (int r = 0; r < 4; r++) tl[r] = thrS[w * 8 + q * 4 + r];
#pragma unroll
        for (int g = 0; g < 4; g++)
#pragma unroll
          for (int r = 0; r < 4; r++) {
            unsigned bit = 1u << (g * 4 + r);
            if ((pend & bit) && acc[g][r] >= tl[r]) pend &= ~bit;
          }
      }
    }
  }

  // final write: handler lane owns row myrow's sorted list
  if (handler) {
    size_t base = ((size_t)b * Nn + n0 + myrow) * Kk;
#pragma unroll
    for (int kk = 0; kk < Kk; kk++) idxout[base + kk] = hix[kk];
  }
}

// ---------------------------------------------------------------- k_stats
// Per-block partial sums (no global atomic contention); k_reduce finishes.
__global__ __launch_bounds__(256) void k_stats(const float* __restrict__ y1,
                                               const float* __restrict__ z,
                                               const int* __restrict__ idxp,
                                               float* __restrict__ parts) {
  __shared__ float rs[4][64];
  __shared__ float rq[4][64];
  int tid = threadIdx.x;
  int o = tid & 63, g = tid >> 6;
  int b = blockIdx.x & 7;                       // XCD swizzle
  int n0 = (blockIdx.x >> 3) << 6;
  const float* y1b = y1 + (size_t)b * Nn * 64;
  float s = 0.f, ss = 0.f;
  for (int t = 0; t < 16; t++) {
    int n = n0 + g + t * 4;
    size_t base = (size_t)b * Nn + n;
    float zv = z[base * 64 + o];
    const int* ip = idxp + base * Kk;
#pragma unroll
    for (int k = 0; k < Kk; k++) {
      int j = ip[k];
      float hv = y1b[(size_t)j * 64 + o] + zv;
      s += hv;
      ss = fmaf(hv, hv, ss);
    }
  }
  rs[g][o] = s;
  rq[g][o] = ss;
  __syncthreads();
  if (tid < 64) {
    parts[(size_t)blockIdx.x * 128 + tid] = rs[0][tid] + rs[1][tid] + rs[2][tid] + rs[3][tid];
    parts[(size_t)blockIdx.x * 128 + 64 + tid] = rq[0][tid] + rq[1][tid] + rq[2][tid] + rq[3][tid];
  }
}

// ---------------------------------------------------------------- k_reduce
__global__ __launch_bounds__(128) void k_reduce(const float* __restrict__ parts,
                                                float* __restrict__ stats) {
  int tid = threadIdx.x;                         // [0,128)
  float s = 0.f;
  for (int i = 0; i < 512; i += 4) {
    s += parts[(size_t)i * 128 + tid] + parts[(size_t)(i + 1) * 128 + tid] +
         parts[(size_t)(i + 2) * 128 + tid] + parts[(size_t)(i + 3) * 128 + tid];
  }
  stats[tid] = s;
}

// ---------------------------------------------------------------- k_out
__global__ __launch_bounds__(256) void k_out(const float* __restrict__ y1,
                                             const float* __restrict__ z,
                                             const int* __restrict__ idxp,
                                             const float* __restrict__ stats,
                                             const float* __restrict__ gamma,
                                             const float* __restrict__ beta,
                                             float* __restrict__ out) {
  __shared__ float T[64][65];
  int tid = threadIdx.x;
  int lane = tid & 63;
  int w = tid >> 6;
  int b = blockIdx.x & 7;                       // XCD swizzle
  int n0 = (blockIdx.x >> 3) << 6;
  int o = lane;
  const float inv = 1.0f / (float)NTOT;
  float mean = stats[o] * inv;
  float var = fmaf(-mean, mean, stats[64 + o] * inv);
  float sc = gamma[o] * rsqrtf(var + 1e-5f);
  float bi = fmaf(-mean, sc, beta[o]);
  const float* y1b = y1 + (size_t)b * Nn * 64;
  for (int t = 0; t < 16; t++) {
    int nl = w + t * 4;
    size_t base = (size_t)b * Nn + n0 + nl;
    float zv = z[base * 64 + o];
    const int* ip = idxp + base * Kk;
    float mv = -INFINITY;
#pragma unroll
    for (int k = 0; k < Kk; k++) {
      int j = ip[k];
      float hv = y1b[(size_t)j * 64 + o] + zv;
      float hn = fmaf(hv, sc, bi);
      float a = (hn >= 0.f) ? hn : 0.2f * hn;
      mv = fmaxf(mv, a);
    }
    T[o][nl] = mv;
  }
  __syncthreads();
  for (int t = 0; t < 16; t++) {
    int oo = w * 16 + t;
    out[((size_t)b * Oo + oo) * Nn + n0 + lane] = T[oo][lane];
  }
}

// ---------------------------------------------------------------- launch
extern "C" void kernel_launch(void* const* d_in, const int* in_sizes, int n_in,
                              void* d_out, int out_size, void* d_ws, size_t ws_size,
                              hipStream_t stream) {
  const float* x = (const float*)d_in[0];
  const float* W = (const float*)d_in[1];
  const float* gamma = (const float*)d_in[2];
  const float* beta = (const float*)d_in[3];
  // d_in[4] is k (=20), baked in as Kk.

  // workspace layout (bytes):
  //   xhi  : [0,        4194304)  bf16 [b][n][c]  \ dead after k_knn;
  //   xmid : [4194304,  8388608)  bf16 [b][n][c]   } y1 overlays [0,8M),
  //   xlo  : [8388608, 12582912)  bf16 [b][n][c]  / z overlays [8M,16M)
  //   y1   : [0,        8388608)  B*N*O fp32  (k_y1z, after k_knn)
  //   z    : [8388608, 16777216)  B*N*O fp32  (k_y1z, after k_knn)
  //   sq   : [16777216,16908288)  B*N fp32
  //   stats: [16908288,16908800)  128 fp32
  //   idx20: [16908800,19530240)  B*N*K int32
  //   parts: [19530240,19792384)  512*128 fp32
  char* ws = (char*)d_ws;
  unsigned short* xhi = (unsigned short*)ws;
  unsigned short* xmid = (unsigned short*)(ws + 4194304);
  unsigned short* xlo = (unsigned short*)(ws + 8388608);
  float* y1 = (float*)ws;
  float* z = (float*)(ws + 8388608);
  float* sq = (float*)(ws + 16777216);
  float* stats = (float*)(ws + 16908288);
  int* idx = (int*)(ws + 16908800);
  float* parts = (float*)(ws + 19530240);
  float* out = (float*)d_out;

  k_split<<<Bn * (Nn / 64), 256, 0, stream>>>(x, xhi, xmid, xlo);
  k_sq<<<(Bn * Nn) / 256, 256, 0, stream>>>(x, sq);
  k_knn<<<Bn * (Nn / 32), 256, 0, stream>>>(xhi, xmid, xlo, sq, idx);
  k_y1z<<<Bn * (Nn / 64), 256, 0, stream>>>(x, W, y1, z);
  k_stats<<<Bn * (Nn / 64), 256, 0, stream>>>(y1, z, idx, parts);
  k_reduce<<<1, 128, 0, stream>>>(parts, stats);
  k_out<<<Bn * (Nn / 64), 256, 0, stream>>>(y1, z, idx, stats, gamma, beta, out);
}